// Round 8
// baseline (103.951 us; speedup 1.0000x reference)
//
#include <hip/hip_runtime.h>
#include <math.h>

typedef unsigned short u16;
typedef unsigned int   u32;

using bf16x8 = __attribute__((ext_vector_type(8))) short;
using f32x4  = __attribute__((ext_vector_type(4))) float;

#define NB   64      // batch
#define NE   8       // experts
#define DIN  320
#define NP   196     // real patches per image
#define MPAD 256     // padded row stride of patches buffer
#define CK   768     // inner dim (C*P*P)
#define CN   768     // out features
#define NKT  24      // K-steps of 32

#define GATE_BLOCKS  8
#define WCONV_BLOCKS 1152   // 8*768*768 / (16*256)
#define PATCH_BLOCKS 2352   // 64*196*48 / 256

__device__ __forceinline__ u16 f2bf(float f) {
    u32 u = __builtin_bit_cast(u32, f);
    u += 0x7fffu + ((u >> 16) & 1u);
    return (u16)(u >> 16);
}

// ---------------- prep1: gate1 + wconv + patchify (one low-LDS dispatch) ----------------
__global__ __launch_bounds__(256) void prep1_kernel(
    const float* __restrict__ x,
    const float* __restrict__ g,
    const float* __restrict__ noise,
    const float* __restrict__ w_gate,
    const float* __restrict__ w_noise,
    const float* __restrict__ w_exp,
    float* __restrict__ gCl, float* __restrict__ gSd, float* __restrict__ gNy,
    u16* __restrict__ patches,
    u16* __restrict__ wb)
{
    __shared__ float sW[DIN][NE + 1];    // +1 pad: no 8-way bank conflict
    __shared__ float sWn[DIN][NE + 1];
    const int t = threadIdx.x;
    int bid = blockIdx.x;

    if (bid < GATE_BLOCKS) {
        // gate stage 1: 8 blocks x 8 images; thread=(pair,q), q sums 80 dims
        for (int i = t; i < DIN * NE; i += 256) {
            sW[i >> 3][i & 7]  = w_gate[i];
            sWn[i >> 3][i & 7] = w_noise[i];
        }
        __syncthreads();
        const int pair = t >> 2, q = t & 3;
        const int bl = pair >> 3, e = pair & 7;
        const int b = bid * 8 + bl;
        float cl = 0.f, nz = 0.f;
        const float* gr = g + b * DIN + q * 80;
        #pragma unroll 4
        for (int j = 0; j < 80; ++j) {
            float gv = gr[j];
            cl = fmaf(gv, sW[q * 80 + j][e], cl);
            nz = fmaf(gv, sWn[q * 80 + j][e], nz);
        }
        cl += __shfl_xor(cl, 1); cl += __shfl_xor(cl, 2);
        nz += __shfl_xor(nz, 1); nz += __shfl_xor(nz, 2);
        if (q == 0) {
            int p = b * NE + e;
            // jax.nn.softplus == max(x,0)+log1p(exp(-|x|))
            float sd = fmaxf(nz, 0.f) + log1pf(expf(-fabsf(nz))) + 0.01f;
            gCl[p] = cl; gSd[p] = sd;
            gNy[p] = fmaf(noise[p], sd, cl);
        }
        return;
    }
    bid -= GATE_BLOCKS;

    if (bid < WCONV_BLOCKS) {
        // w_exp fp32 -> bf16, 16 elems/thread (64B read, 32B write)
        int idx = bid * 256 + t;
        const float* src = w_exp + (size_t)idx * 16;
        u16* dst = wb + (size_t)idx * 16;
        float4 f0 = *reinterpret_cast<const float4*>(src);
        float4 f1 = *reinterpret_cast<const float4*>(src + 4);
        float4 f2 = *reinterpret_cast<const float4*>(src + 8);
        float4 f3 = *reinterpret_cast<const float4*>(src + 12);
        uint4 o0, o1;
        o0.x = (u32)f2bf(f0.x) | ((u32)f2bf(f0.y) << 16);
        o0.y = (u32)f2bf(f0.z) | ((u32)f2bf(f0.w) << 16);
        o0.z = (u32)f2bf(f1.x) | ((u32)f2bf(f1.y) << 16);
        o0.w = (u32)f2bf(f1.z) | ((u32)f2bf(f1.w) << 16);
        o1.x = (u32)f2bf(f2.x) | ((u32)f2bf(f2.y) << 16);
        o1.y = (u32)f2bf(f2.z) | ((u32)f2bf(f2.w) << 16);
        o1.z = (u32)f2bf(f3.x) | ((u32)f2bf(f3.y) << 16);
        o1.w = (u32)f2bf(f3.z) | ((u32)f2bf(f3.w) << 16);
        *reinterpret_cast<uint4*>(dst)     = o0;
        *reinterpret_cast<uint4*>(dst + 8) = o1;
        return;
    }
    bid -= WCONV_BLOCKS;

    // patchify -> bf16 (real rows only). thread = (b, p, c, ph), 16 px row.
    int idx = bid * 256 + t;
    int ph = idx & 15;
    int c  = (idx >> 4) % 3;
    int p  = (idx / 48) % NP;
    int b  = idx / (48 * NP);
    int gh = p / 14, gw = p % 14;
    const float* src = x + (((size_t)(b * 3 + c) * 224 + gh * 16 + ph) * 224 + gw * 16);
    u16* dst = patches + ((size_t)(b * MPAD + p)) * CK + c * 256 + ph * 16;
    float4 f0 = *reinterpret_cast<const float4*>(src);
    float4 f1 = *reinterpret_cast<const float4*>(src + 4);
    float4 f2 = *reinterpret_cast<const float4*>(src + 8);
    float4 f3 = *reinterpret_cast<const float4*>(src + 12);
    uint4 o0, o1;
    o0.x = (u32)f2bf(f0.x) | ((u32)f2bf(f0.y) << 16);
    o0.y = (u32)f2bf(f0.z) | ((u32)f2bf(f0.w) << 16);
    o0.z = (u32)f2bf(f1.x) | ((u32)f2bf(f1.y) << 16);
    o0.w = (u32)f2bf(f1.z) | ((u32)f2bf(f1.w) << 16);
    o1.x = (u32)f2bf(f2.x) | ((u32)f2bf(f2.y) << 16);
    o1.y = (u32)f2bf(f2.z) | ((u32)f2bf(f2.w) << 16);
    o1.z = (u32)f2bf(f3.x) | ((u32)f2bf(f3.y) << 16);
    o1.w = (u32)f2bf(f3.z) | ((u32)f2bf(f3.w) << 16);
    *reinterpret_cast<uint4*>(dst)     = o0;
    *reinterpret_cast<uint4*>(dst + 8) = o1;
}

// ---------------- gate2: top-2, probs, loss, eid, expert-sorted perm ----------------
__global__ __launch_bounds__(512) void gate2_kernel(
    const float* __restrict__ gCl,
    const float* __restrict__ gSd,
    const float* __restrict__ gNy,
    int* __restrict__ eid,
    int* __restrict__ perm,
    float* __restrict__ loss_out)
{
    __shared__ float sNy[NB][NE];
    __shared__ float sProb[NB][NE];
    __shared__ int   sTop[NB];
    __shared__ float sImp[NE], sLoad[NE];
    const int t = threadIdx.x;            // 512 = one (b,e) pair each
    const int b = t >> 3, e = t & 7;
    float cl = gCl[t], sd = gSd[t], ny = gNy[t];
    sNy[b][e] = ny;
    __syncthreads();
    float v1 = -1e30f, v2 = -1e30f; int i1 = 0;
    #pragma unroll
    for (int k2 = 0; k2 < NE; ++k2) {
        float v = sNy[b][k2];
        if (v > v1) { v2 = v1; v1 = v; i1 = k2; }
        else if (v > v2) { v2 = v; }
    }
    if (e == 0) { sTop[b] = i1; eid[b] = i1; }
    // is_in: noisy > 2nd-largest (thr_in=v2); else threshold = largest (v1)
    float thr = (ny > v2) ? v2 : v1;
    float z = (cl - thr) / sd;
    sProb[b][e] = 0.5f * (1.0f + erff(z * 0.7071067811865476f));
    __syncthreads();
    if (t < NE) {
        float imp = 0.f, ld = 0.f;
        for (int i = 0; i < NB; ++i) {
            imp += (sTop[i] == t) ? 1.0f : 0.0f;
            ld  += sProb[i][t];
        }
        sImp[t] = imp; sLoad[t] = ld;
    }
    __syncthreads();
    if (t == 0) {
        float mi = 0.f, ml = 0.f;
        for (int k2 = 0; k2 < NE; ++k2) { mi += sImp[k2]; ml += sLoad[k2]; }
        mi *= (1.0f / NE); ml *= (1.0f / NE);
        float vi = 0.f, vl = 0.f;
        for (int k2 = 0; k2 < NE; ++k2) {
            float d1 = sImp[k2] - mi;  vi += d1 * d1;
            float d2 = sLoad[k2] - ml; vl += d2 * d2;
        }
        vi *= (1.0f / (NE - 1)); vl *= (1.0f / (NE - 1));  // ddof=1
        loss_out[0] = (vi / (mi * mi + 1e-10f) + vl / (ml * ml + 1e-10f)) * 0.01f;
        // expert-sorted stable permutation of images (L2 locality for B)
        int off[NE]; int s = 0;
        #pragma unroll
        for (int k2 = 0; k2 < NE; ++k2) { off[k2] = s; s += (int)sImp[k2]; }
        for (int i = 0; i < NB; ++i) perm[off[sTop[i]]++] = i;
    }
}

// ---------------- reg-streaming expert GEMM: no LDS, no barriers ----------------
// 768 blocks -> (slot v/12 -> image perm[], m-tile 0/1, n-tile 0..5).
// 4 waves, each owns a 64x64 tile; A and B fragments stream L2->reg
// (global_load_dwordx4 per frag, exact MFMA layout), reg-double-buffered,
// manual 2x unroll. s_setprio around MFMA clusters (free-running waves).
__global__ __launch_bounds__(256, 3) void gemm_kernel(
    const u16* __restrict__ patches,
    const u16* __restrict__ wbf,
    const float* __restrict__ b_exp,
    const int* __restrict__ eid,
    const int* __restrict__ perm,
    float* __restrict__ out)
{
    const int id = blockIdx.x;
    // bijective XCD swizzle: 96 consecutive virtual blocks (=8 sorted slots) per XCD
    const int v  = (id & 7) * 96 + (id >> 3);
    const int b  = perm[v / 12];
    const int rr = v % 12;
    const int m0 = (rr / 6) * 128;
    const int n0 = (rr % 6) * 128;
    const int e  = eid[b];

    const int t  = threadIdx.x;
    const int l  = t & 63;
    const int w  = t >> 6;
    const int wm = w >> 1;        // 0/1 -> m half
    const int wn = w & 1;         // 0/1 -> n half
    const int lr = l & 15;        // fragment row
    const int lk = l >> 4;        // k-slice (8 bf16)

    // per-fragment lane pointers (advance by kt*32 u16 per K-step)
    const u16* aP[4];
    const u16* bP[4];
    #pragma unroll
    for (int fm = 0; fm < 4; ++fm)
        aP[fm] = patches + ((size_t)b * MPAD + m0 + wm * 64 + fm * 16 + lr) * CK + lk * 8;
    #pragma unroll
    for (int fn = 0; fn < 4; ++fn)
        bP[fn] = wbf + (size_t)e * (CK * CN)
               + (size_t)(n0 + wn * 64 + fn * 16 + lr) * CK + lk * 8;

    f32x4 acc[4][4];
    #pragma unroll
    for (int fm = 0; fm < 4; ++fm)
        #pragma unroll
        for (int fn = 0; fn < 4; ++fn)
            acc[fm][fn] = (f32x4){0.f, 0.f, 0.f, 0.f};

    bf16x8 aE[4], bE[4], aO[4], bO[4];
    #pragma unroll
    for (int f = 0; f < 4; ++f) {
        aE[f] = *reinterpret_cast<const bf16x8*>(aP[f]);
        bE[f] = *reinterpret_cast<const bf16x8*>(bP[f]);
    }

    int kt = 0;
    for (; kt < NKT - 2; kt += 2) {
        #pragma unroll
        for (int f = 0; f < 4; ++f) {
            aO[f] = *reinterpret_cast<const bf16x8*>(aP[f] + (kt + 1) * 32);
            bO[f] = *reinterpret_cast<const bf16x8*>(bP[f] + (kt + 1) * 32);
        }
        __builtin_amdgcn_s_setprio(1);
        #pragma unroll
        for (int fm = 0; fm < 4; ++fm)
            #pragma unroll
            for (int fn = 0; fn < 4; ++fn)
                acc[fm][fn] = __builtin_amdgcn_mfma_f32_16x16x32_bf16(
                    aE[fm], bE[fn], acc[fm][fn], 0, 0, 0);
        __builtin_amdgcn_s_setprio(0);
        #pragma unroll
        for (int f = 0; f < 4; ++f) {
            aE[f] = *reinterpret_cast<const bf16x8*>(aP[f] + (kt + 2) * 32);
            bE[f] = *reinterpret_cast<const bf16x8*>(bP[f] + (kt + 2) * 32);
        }
        __builtin_amdgcn_s_setprio(1);
        #pragma unroll
        for (int fm = 0; fm < 4; ++fm)
            #pragma unroll
            for (int fn = 0; fn < 4; ++fn)
                acc[fm][fn] = __builtin_amdgcn_mfma_f32_16x16x32_bf16(
                    aO[fm], bO[fn], acc[fm][fn], 0, 0, 0);
        __builtin_amdgcn_s_setprio(0);
    }
    // kt == NKT-2: load last odd tile, compute both
    {
        #pragma unroll
        for (int f = 0; f < 4; ++f) {
            aO[f] = *reinterpret_cast<const bf16x8*>(aP[f] + (NKT - 1) * 32);
            bO[f] = *reinterpret_cast<const bf16x8*>(bP[f] + (NKT - 1) * 32);
        }
        __builtin_amdgcn_s_setprio(1);
        #pragma unroll
        for (int fm = 0; fm < 4; ++fm)
            #pragma unroll
            for (int fn = 0; fn < 4; ++fn)
                acc[fm][fn] = __builtin_amdgcn_mfma_f32_16x16x32_bf16(
                    aE[fm], bE[fn], acc[fm][fn], 0, 0, 0);
        #pragma unroll
        for (int fm = 0; fm < 4; ++fm)
            #pragma unroll
            for (int fn = 0; fn < 4; ++fn)
                acc[fm][fn] = __builtin_amdgcn_mfma_f32_16x16x32_bf16(
                    aO[fm], bO[fn], acc[fm][fn], 0, 0, 0);
        __builtin_amdgcn_s_setprio(0);
    }

    // ---- store: bias + eps-replace, rows < 196 only ----
    const int r4 = (l >> 4) * 4;
    #pragma unroll
    for (int fm = 0; fm < 4; ++fm) {
        int mb = m0 + wm * 64 + fm * 16 + r4;
        #pragma unroll
        for (int fn = 0; fn < 4; ++fn) {
            int col = n0 + wn * 64 + fn * 16 + (l & 15);
            float bias = b_exp[e * CN + col];
            #pragma unroll
            for (int q = 0; q < 4; ++q) {
                int mrow = mb + q;
                if (mrow < NP) {
                    float vv = acc[fm][fn][q] + bias;
                    if (vv == 0.0f) vv = 2.220446049250313e-16f;
                    out[((size_t)b * NP + mrow) * CN + col] = vv;
                }
            }
        }
    }
}

extern "C" void kernel_launch(void* const* d_in, const int* in_sizes, int n_in,
                              void* d_out, int out_size, void* d_ws, size_t ws_size,
                              hipStream_t stream) {
    const float* x       = (const float*)d_in[0];
    const float* g       = (const float*)d_in[1];
    const float* noise   = (const float*)d_in[2];
    const float* w_gate  = (const float*)d_in[3];
    const float* w_noise = (const float*)d_in[4];
    const float* w_exp   = (const float*)d_in[5];
    const float* b_exp   = (const float*)d_in[6];
    float* out = (float*)d_out;

    char* ws = (char*)d_ws;
    int*   eid     = (int*)ws;                    // 256 B
    int*   perm    = (int*)(ws + 256);            // 256 B
    float* gCl     = (float*)(ws + 512);          // 2 KB
    float* gSd     = (float*)(ws + 2560);         // 2 KB
    float* gNy     = (float*)(ws + 4608);         // 2 KB
    u16*   patches = (u16*)(ws + 8192);                               // 64*256*768*2
    u16*   wbf     = (u16*)(ws + 8192 + (size_t)NB * MPAD * CK * 2);  // 8*768*768*2

    hipLaunchKernelGGL(prep1_kernel,
                       dim3(GATE_BLOCKS + WCONV_BLOCKS + PATCH_BLOCKS), dim3(256), 0, stream,
                       x, g, noise, w_gate, w_noise, w_exp, gCl, gSd, gNy, patches, wbf);
    hipLaunchKernelGGL(gate2_kernel, dim3(1), dim3(512), 0, stream,
                       gCl, gSd, gNy, eid, perm, out + (size_t)NB * NP * CN);
    hipLaunchKernelGGL(gemm_kernel, dim3(768), dim3(256), 0, stream,
                       patches, wbf, b_exp, eid, perm, out);
}

// Round 9
// 74.561 us; speedup vs baseline: 1.3942x; 1.3942x over previous
//
#include <hip/hip_runtime.h>
#include <math.h>

typedef unsigned short u16;
typedef unsigned int   u32;

using bf16x8 = __attribute__((ext_vector_type(8))) short;
using f32x4  = __attribute__((ext_vector_type(4))) float;

#define NB   64      // batch
#define NE   8       // experts
#define DIN  320
#define NP   196     // real patches per image
#define CK   768     // inner dim (C*P*P)
#define CN   768     // out features
#define NKT  24      // K-blocks of 32

#define GATE_BLOCKS  8
#define WCONV_BLOCKS 1152   // 8*768*768 / (16*256)
#define PACK_BLOCKS  1024   // 64 images x 16 frag-rows

__device__ __forceinline__ u16 f2bf(float f) {
    u32 u = __builtin_bit_cast(u32, f);
    u += 0x7fffu + ((u >> 16) & 1u);
    return (u16)(u >> 16);
}

__device__ __forceinline__ void gload16(const void* g, void* l) {
    __builtin_amdgcn_global_load_lds(
        (const __attribute__((address_space(1))) void*)g,
        (__attribute__((address_space(3))) void*)l, 16, 0, 0);
}

// ---------------- prep1: gate1 + wconv + fragment-packing patchify ----------------
// A-packed layout: chunk(b, fr, kb) = 1KB at ((b*16+fr)*24+kb)*1024;
// within chunk byte l*16 holds row fr*16+(l&15), k = kb*32+(l>>4)*8 .. +8.
__global__ __launch_bounds__(256) void prep1_kernel(
    const float* __restrict__ x,
    const float* __restrict__ g,
    const float* __restrict__ noise,
    const float* __restrict__ w_gate,
    const float* __restrict__ w_noise,
    const float* __restrict__ w_exp,
    float* __restrict__ gCl, float* __restrict__ gSd, float* __restrict__ gNy,
    u16* __restrict__ apk,
    u16* __restrict__ wb)
{
    __shared__ char smem[24704];    // union: gate 23KB | pack 24KB
    const int t = threadIdx.x;
    int bid = blockIdx.x;

    if (bid < GATE_BLOCKS) {
        // gate stage 1: 8 blocks x 8 images; thread=(pair,q), q sums 80 dims
        float (*sW)[NE + 1]  = (float (*)[NE + 1])smem;
        float (*sWn)[NE + 1] = sW + DIN;
        for (int i = t; i < DIN * NE; i += 256) {
            sW[i >> 3][i & 7]  = w_gate[i];
            sWn[i >> 3][i & 7] = w_noise[i];
        }
        __syncthreads();
        const int pair = t >> 2, q = t & 3;
        const int bl = pair >> 3, e = pair & 7;
        const int b = bid * 8 + bl;
        float cl = 0.f, nz = 0.f;
        const float* gr = g + b * DIN + q * 80;
        #pragma unroll 4
        for (int j = 0; j < 80; ++j) {
            float gv = gr[j];
            cl = fmaf(gv, sW[q * 80 + j][e], cl);
            nz = fmaf(gv, sWn[q * 80 + j][e], nz);
        }
        cl += __shfl_xor(cl, 1); cl += __shfl_xor(cl, 2);
        nz += __shfl_xor(nz, 1); nz += __shfl_xor(nz, 2);
        if (q == 0) {
            int p = b * NE + e;
            // jax.nn.softplus == max(x,0)+log1p(exp(-|x|))
            float sd = fmaxf(nz, 0.f) + log1pf(expf(-fabsf(nz))) + 0.01f;
            gCl[p] = cl; gSd[p] = sd;
            gNy[p] = fmaf(noise[p], sd, cl);
        }
        return;
    }
    bid -= GATE_BLOCKS;

    if (bid < WCONV_BLOCKS) {
        // w_exp fp32 -> bf16 row-major, 16 elems/thread
        int idx = bid * 256 + t;
        const float* src = w_exp + (size_t)idx * 16;
        u16* dst = wb + (size_t)idx * 16;
        float4 f0 = *reinterpret_cast<const float4*>(src);
        float4 f1 = *reinterpret_cast<const float4*>(src + 4);
        float4 f2 = *reinterpret_cast<const float4*>(src + 8);
        float4 f3 = *reinterpret_cast<const float4*>(src + 12);
        uint4 o0, o1;
        o0.x = (u32)f2bf(f0.x) | ((u32)f2bf(f0.y) << 16);
        o0.y = (u32)f2bf(f0.z) | ((u32)f2bf(f0.w) << 16);
        o0.z = (u32)f2bf(f1.x) | ((u32)f2bf(f1.y) << 16);
        o0.w = (u32)f2bf(f1.z) | ((u32)f2bf(f1.w) << 16);
        o1.x = (u32)f2bf(f2.x) | ((u32)f2bf(f2.y) << 16);
        o1.y = (u32)f2bf(f2.z) | ((u32)f2bf(f2.w) << 16);
        o1.z = (u32)f2bf(f3.x) | ((u32)f2bf(f3.y) << 16);
        o1.w = (u32)f2bf(f3.z) | ((u32)f2bf(f3.w) << 16);
        *reinterpret_cast<uint4*>(dst)     = o0;
        *reinterpret_cast<uint4*>(dst + 8) = o1;
        return;
    }
    bid -= WCONV_BLOCKS;

    // ---- packing patchify: block = (image b, frag-row fr); 16 rows x 768 K ----
    {
        char* pk = smem;   // 24KB staging
        const int b  = bid >> 4;
        const int fr = bid & 15;
        #pragma unroll
        for (int s = 0; s < 3; ++s) {
            int u  = t + s * 256;            // u = (lr*3 + c)*16 + ph
            int lr = u / 48;
            int c  = (u >> 4) % 3;
            int ph = u & 15;
            int p  = fr * 16 + lr; if (p > NP - 1) p = NP - 1;  // pad rows: dup of 195
            const float* src = x + ((size_t)(b * 3 + c) * 224 + (p / 14) * 16 + ph) * 224
                                 + (p % 14) * 16;
            float4 f0 = *reinterpret_cast<const float4*>(src);
            float4 f1 = *reinterpret_cast<const float4*>(src + 4);
            float4 f2 = *reinterpret_cast<const float4*>(src + 8);
            float4 f3 = *reinterpret_cast<const float4*>(src + 12);
            uint4 o0, o1;
            o0.x = (u32)f2bf(f0.x) | ((u32)f2bf(f0.y) << 16);
            o0.y = (u32)f2bf(f0.z) | ((u32)f2bf(f0.w) << 16);
            o0.z = (u32)f2bf(f1.x) | ((u32)f2bf(f1.y) << 16);
            o0.w = (u32)f2bf(f1.z) | ((u32)f2bf(f1.w) << 16);
            o1.x = (u32)f2bf(f2.x) | ((u32)f2bf(f2.y) << 16);
            o1.y = (u32)f2bf(f2.z) | ((u32)f2bf(f2.w) << 16);
            o1.z = (u32)f2bf(f3.x) | ((u32)f2bf(f3.y) << 16);
            o1.w = (u32)f2bf(f3.z) | ((u32)f2bf(f3.w) << 16);
            // k = c*256 + ph*16 + pw -> kb = c*8 + (ph>>1), lk0 = (ph&1)*2
            u32 base = (u32)((c * 8 + (ph >> 1)) * 1024 + ((ph & 1) * 2) * 256 + lr * 16);
            *reinterpret_cast<uint4*>(pk + base)       = o0;
            *reinterpret_cast<uint4*>(pk + base + 256) = o1;
        }
        __syncthreads();
        char* dst = (char*)apk + ((size_t)(b * 16 + fr) * 24) * 1024;
        #pragma unroll
        for (int s = 0; s < 6; ++s)
            *reinterpret_cast<uint4*>(dst + t * 16 + s * 4096) =
                *reinterpret_cast<const uint4*>(pk + t * 16 + s * 4096);
    }
}

// ---------------- gate2: loss only (off critical path, runs last) ----------------
__global__ __launch_bounds__(512) void gate2_kernel(
    const float* __restrict__ gCl,
    const float* __restrict__ gSd,
    const float* __restrict__ gNy,
    float* __restrict__ loss_out)
{
    __shared__ float sNy[NB][NE];
    __shared__ float sProb[NB][NE];
    __shared__ int   sTop[NB];
    __shared__ float sImp[NE], sLoad[NE];
    const int t = threadIdx.x;            // 512 = one (b,e) pair each
    const int b = t >> 3, e = t & 7;
    float cl = gCl[t], sd = gSd[t], ny = gNy[t];
    sNy[b][e] = ny;
    __syncthreads();
    float v1 = -1e30f, v2 = -1e30f; int i1 = 0;
    #pragma unroll
    for (int k2 = 0; k2 < NE; ++k2) {
        float v = sNy[b][k2];
        if (v > v1) { v2 = v1; v1 = v; i1 = k2; }
        else if (v > v2) { v2 = v; }
    }
    if (e == 0) sTop[b] = i1;
    // is_in: noisy > 2nd-largest (thr_in=v2); else threshold = largest (v1)
    float thr = (ny > v2) ? v2 : v1;
    float z = (cl - thr) / sd;
    sProb[b][e] = 0.5f * (1.0f + erff(z * 0.7071067811865476f));
    __syncthreads();
    if (t < NE) {
        float imp = 0.f, ld = 0.f;
        for (int i = 0; i < NB; ++i) {
            imp += (sTop[i] == t) ? 1.0f : 0.0f;
            ld  += sProb[i][t];
        }
        sImp[t] = imp; sLoad[t] = ld;
    }
    __syncthreads();
    if (t == 0) {
        float mi = 0.f, ml = 0.f;
        for (int k2 = 0; k2 < NE; ++k2) { mi += sImp[k2]; ml += sLoad[k2]; }
        mi *= (1.0f / NE); ml *= (1.0f / NE);
        float vi = 0.f, vl = 0.f;
        for (int k2 = 0; k2 < NE; ++k2) {
            float d1 = sImp[k2] - mi;  vi += d1 * d1;
            float d2 = sLoad[k2] - ml; vl += d2 * d2;
        }
        vi *= (1.0f / (NE - 1)); vl *= (1.0f / (NE - 1));  // ddof=1
        loss_out[0] = (vi / (mi * mi + 1e-10f) + vl / (ml * ml + 1e-10f)) * 0.01f;
    }
}

// ---------------- expert GEMM: packed-A from L2 (reg dbuf) + B via LDS tri-buffer ----------------
// one K-step: stage B(j+2)->buf[(j+2)%3], load A(j+1)->Anext (coalesced 1KB
// wave loads), vmcnt(6) [steady leftover B(j+1)x2 + A(j)x4], ONE barrier,
// then 4 ds_read B-frags + 16 MFMA with Acur.
__device__ __forceinline__ void kstep(
    int j, char* sm, u32 bufc, u32 bufs,
    const u16* bS0, const u16* bS1, u32 bLds,
    const char* const (&aB)[4], const u32 (&bOff)[4],
    bf16x8 (&Acur)[4], bf16x8 (&Anext)[4], f32x4 (&acc)[4][4], bool last)
{
    int js = j + 2; if (js > NKT - 1) js = NKT - 1;   // clamp: redundant re-loads
    int ja = j + 1; if (ja > NKT - 1) ja = NKT - 1;
    gload16(bS0 + js * 32, sm + bufs + bLds);
    gload16(bS1 + js * 32, sm + bufs + bLds + 1024);
    #pragma unroll
    for (int fm = 0; fm < 4; ++fm)
        Anext[fm] = *reinterpret_cast<const bf16x8*>(aB[fm] + ja * 1024);
    __builtin_amdgcn_sched_barrier(0);
    if (last) asm volatile("s_waitcnt vmcnt(0)" ::: "memory");
    else      asm volatile("s_waitcnt vmcnt(6)" ::: "memory");
    __builtin_amdgcn_s_barrier();
    bf16x8 bfr[4];
    #pragma unroll
    for (int fn = 0; fn < 4; ++fn)
        bfr[fn] = *reinterpret_cast<const bf16x8*>(sm + bufc + bOff[fn]);
    #pragma unroll
    for (int fm = 0; fm < 4; ++fm)
        #pragma unroll
        for (int fn = 0; fn < 4; ++fn)
            acc[fm][fn] = __builtin_amdgcn_mfma_f32_16x16x32_bf16(
                Acur[fm], bfr[fn], acc[fm][fn], 0, 0, 0);
}

__global__ __launch_bounds__(256) void gemm_kernel(
    const u16* __restrict__ apk,
    const u16* __restrict__ wbf,
    const float* __restrict__ b_exp,
    const float* __restrict__ gNy,
    float* __restrict__ out)
{
    __shared__ char sB[3 * 8192];

    const int id = blockIdx.x;
    // bijective XCD swizzle: 96 consecutive virtual blocks (=8 images) per XCD
    const int v  = (id & 7) * 96 + (id >> 3);
    const int b  = v / 12;
    const int rr = v % 12;
    const int mt = rr / 6;            // m-tile 0/1
    const int n0 = (rr % 6) * 128;

    // expert id: recompute argmax of gNy[b] (removes gate2 from critical path;
    // same strict-> scan order as gate2 -> identical tie-breaking)
    int e = 0;
    {
        float v1 = -1e30f;
        #pragma unroll
        for (int k2 = 0; k2 < NE; ++k2) {
            float vv = gNy[b * NE + k2];
            if (vv > v1) { v1 = vv; e = k2; }
        }
    }

    const int t  = threadIdx.x;
    const int l  = t & 63;
    const int w  = t >> 6;
    const int wm = w >> 1;
    const int wn = w & 1;
    char* sm = sB;

    // ---- B staging (R5-proven): rows rs=(w*32)+(l>>2), +16; chunk-swizzled src ----
    const int rs = (w << 5) + (l >> 2);
    const u32 cg = (u32)((l & 3) ^ (l >> 4));
    const u16* bS0 = wbf + (size_t)e * (CK * CN) + (size_t)(n0 + rs) * CK + cg * 8;
    const u16* bS1 = bS0 + (size_t)16 * CK;
    const u32 bLds = ((u32)w << 11) + ((u32)l << 4);

    // ---- A fragment chunk bases (packed layout; lane offset l*16) ----
    const char* aB[4];
    #pragma unroll
    for (int fm = 0; fm < 4; ++fm)
        aB[fm] = (const char*)apk
               + ((size_t)((b * 16 + mt * 8 + wm * 4 + fm) * 24)) * 1024 + l * 16;

    // ---- B frag read offsets (chunk swizzle c = (l>>4) ^ ((row>>2)&3)) ----
    u32 bOff[4];
    #pragma unroll
    for (int fn = 0; fn < 4; ++fn) {
        int row = wn * 64 + fn * 16 + (l & 15);
        bOff[fn] = (u32)(row * 64) + (((u32)(l >> 4) ^ (u32)((row >> 2) & 3)) << 4);
    }

    f32x4 acc[4][4];
    #pragma unroll
    for (int fm = 0; fm < 4; ++fm)
        #pragma unroll
        for (int fn = 0; fn < 4; ++fn)
            acc[fm][fn] = (f32x4){0.f, 0.f, 0.f, 0.f};

    bf16x8 rA[4], rB[4];

    // ---- prologue: B(0)->buf0, B(1)->buf1, A(0)->rA ----
    gload16(bS0, sm + bLds);
    gload16(bS1, sm + bLds + 1024);
    gload16(bS0 + 32, sm + 8192 + bLds);
    gload16(bS1 + 32, sm + 8192 + bLds + 1024);
    #pragma unroll
    for (int fm = 0; fm < 4; ++fm)
        rA[fm] = *reinterpret_cast<const bf16x8*>(aB[fm]);
    __builtin_amdgcn_sched_barrier(0);

    // ---- main loop: 4 x 6 steps; buffers cycle (0,1,2), A regs alternate ----
    for (int kt = 0; kt < NKT; kt += 6) {
        bool lastgrp = (kt + 6 >= NKT);
        kstep(kt + 0, sm, 0,     16384, bS0, bS1, bLds, aB, bOff, rA, rB, acc, false);
        kstep(kt + 1, sm, 8192,  0,     bS0, bS1, bLds, aB, bOff, rB, rA, acc, false);
        kstep(kt + 2, sm, 16384, 8192,  bS0, bS1, bLds, aB, bOff, rA, rB, acc, false);
        kstep(kt + 3, sm, 0,     16384, bS0, bS1, bLds, aB, bOff, rB, rA, acc, false);
        kstep(kt + 4, sm, 8192,  0,     bS0, bS1, bLds, aB, bOff, rA, rB, acc, false);
        kstep(kt + 5, sm, 16384, 8192,  bS0, bS1, bLds, aB, bOff, rB, rA, acc, lastgrp);
    }

    // ---- store: bias + eps-replace, rows < 196 only ----
    const int r4 = (l >> 4) * 4;
    #pragma unroll
    for (int fm = 0; fm < 4; ++fm) {
        int mb = mt * 128 + wm * 64 + fm * 16 + r4;
        #pragma unroll
        for (int fn = 0; fn < 4; ++fn) {
            int col = n0 + wn * 64 + fn * 16 + (l & 15);
            float bias = b_exp[e * CN + col];
            #pragma unroll
            for (int q = 0; q < 4; ++q) {
                int mrow = mb + q;
                if (mrow < NP) {
                    float vv = acc[fm][fn][q] + bias;
                    if (vv == 0.0f) vv = 2.220446049250313e-16f;
                    out[((size_t)b * NP + mrow) * CN + col] = vv;
                }
            }
        }
    }
}

extern "C" void kernel_launch(void* const* d_in, const int* in_sizes, int n_in,
                              void* d_out, int out_size, void* d_ws, size_t ws_size,
                              hipStream_t stream) {
    const float* x       = (const float*)d_in[0];
    const float* g       = (const float*)d_in[1];
    const float* noise   = (const float*)d_in[2];
    const float* w_gate  = (const float*)d_in[3];
    const float* w_noise = (const float*)d_in[4];
    const float* w_exp   = (const float*)d_in[5];
    const float* b_exp   = (const float*)d_in[6];
    float* out = (float*)d_out;

    char* ws = (char*)d_ws;
    float* gCl = (float*)(ws + 256);          // 2 KB
    float* gSd = (float*)(ws + 2304);         // 2 KB
    float* gNy = (float*)(ws + 4352);         // 2 KB
    u16*   apk = (u16*)(ws + 8192);                               // 64*16*24*1024 B
    u16*   wbf = (u16*)(ws + 8192 + (size_t)NB * 16 * 24 * 1024); // 8*768*768*2

    hipLaunchKernelGGL(prep1_kernel,
                       dim3(GATE_BLOCKS + WCONV_BLOCKS + PACK_BLOCKS), dim3(256), 0, stream,
                       x, g, noise, w_gate, w_noise, w_exp, gCl, gSd, gNy, apk, wbf);
    hipLaunchKernelGGL(gemm_kernel, dim3(768), dim3(256), 0, stream,
                       apk, wbf, b_exp, gNy, out);
    hipLaunchKernelGGL(gate2_kernel, dim3(1), dim3(512), 0, stream,
                       gCl, gSd, gNy, out + (size_t)NB * NP * CN);
}

// Round 10
// 72.838 us; speedup vs baseline: 1.4272x; 1.0237x over previous
//
#include <hip/hip_runtime.h>
#include <math.h>

typedef unsigned short u16;
typedef unsigned int   u32;

using bf16x8 = __attribute__((ext_vector_type(8))) short;
using f32x4  = __attribute__((ext_vector_type(4))) float;

#define NB   64
#define NE   8
#define DIN  320
#define NP   196
#define CK   768
#define CN   768
#define ESTR (768 * 768)

#define GATE_BLOCKS  8
#define WCONV_BLOCKS 1152   // 8*768*768 / (16*256)
#define PATCH_BLOCKS 2352   // 64*196*48 / 256

__device__ __forceinline__ u16 f2bf(float f) {
    u32 u = __builtin_bit_cast(u32, f);
    u += 0x7fffu + ((u >> 16) & 1u);
    return (u16)(u >> 16);
}

__device__ __forceinline__ void gload16(const void* g, void* l) {
    __builtin_amdgcn_global_load_lds(
        (const __attribute__((address_space(1))) void*)g,
        (__attribute__((address_space(3))) void*)l, 16, 0, 0);
}

// ---------------- prep1: gate1 + wconv + row-major patchify ----------------
__global__ __launch_bounds__(256) void prep1_kernel(
    const float* __restrict__ x,
    const float* __restrict__ g,
    const float* __restrict__ noise,
    const float* __restrict__ w_gate,
    const float* __restrict__ w_noise,
    const float* __restrict__ w_exp,
    float* __restrict__ gCl, float* __restrict__ gSd, float* __restrict__ gNy,
    u16* __restrict__ patches,
    u16* __restrict__ wb)
{
    __shared__ float sW[DIN][NE + 1];
    __shared__ float sWn[DIN][NE + 1];
    const int t = threadIdx.x;
    int bid = blockIdx.x;

    if (bid < GATE_BLOCKS) {
        for (int i = t; i < DIN * NE; i += 256) {
            sW[i >> 3][i & 7]  = w_gate[i];
            sWn[i >> 3][i & 7] = w_noise[i];
        }
        __syncthreads();
        const int pair = t >> 2, q = t & 3;
        const int bl = pair >> 3, e = pair & 7;
        const int b = bid * 8 + bl;
        float cl = 0.f, nz = 0.f;
        const float* gr = g + b * DIN + q * 80;
        #pragma unroll 4
        for (int j = 0; j < 80; ++j) {
            float gv = gr[j];
            cl = fmaf(gv, sW[q * 80 + j][e], cl);
            nz = fmaf(gv, sWn[q * 80 + j][e], nz);
        }
        cl += __shfl_xor(cl, 1); cl += __shfl_xor(cl, 2);
        nz += __shfl_xor(nz, 1); nz += __shfl_xor(nz, 2);
        if (q == 0) {
            int p = b * NE + e;
            // jax.nn.softplus == max(x,0)+log1p(exp(-|x|))
            float sd = fmaxf(nz, 0.f) + log1pf(expf(-fabsf(nz))) + 0.01f;
            gCl[p] = cl; gSd[p] = sd;
            gNy[p] = fmaf(noise[p], sd, cl);
        }
        return;
    }
    bid -= GATE_BLOCKS;

    if (bid < WCONV_BLOCKS) {
        int idx = bid * 256 + t;
        const float* src = w_exp + (size_t)idx * 16;
        u16* dst = wb + (size_t)idx * 16;
        float4 f0 = *reinterpret_cast<const float4*>(src);
        float4 f1 = *reinterpret_cast<const float4*>(src + 4);
        float4 f2 = *reinterpret_cast<const float4*>(src + 8);
        float4 f3 = *reinterpret_cast<const float4*>(src + 12);
        uint4 o0, o1;
        o0.x = (u32)f2bf(f0.x) | ((u32)f2bf(f0.y) << 16);
        o0.y = (u32)f2bf(f0.z) | ((u32)f2bf(f0.w) << 16);
        o0.z = (u32)f2bf(f1.x) | ((u32)f2bf(f1.y) << 16);
        o0.w = (u32)f2bf(f1.z) | ((u32)f2bf(f1.w) << 16);
        o1.x = (u32)f2bf(f2.x) | ((u32)f2bf(f2.y) << 16);
        o1.y = (u32)f2bf(f2.z) | ((u32)f2bf(f2.w) << 16);
        o1.z = (u32)f2bf(f3.x) | ((u32)f2bf(f3.y) << 16);
        o1.w = (u32)f2bf(f3.z) | ((u32)f2bf(f3.w) << 16);
        *reinterpret_cast<uint4*>(dst)     = o0;
        *reinterpret_cast<uint4*>(dst + 8) = o1;
        return;
    }
    bid -= WCONV_BLOCKS;

    // patchify -> bf16 row-major [b][256-stride][768], rows < 196 only
    int idx = bid * 256 + t;
    int ph = idx & 15;
    int c  = (idx >> 4) % 3;
    int p  = (idx / 48) % NP;
    int b  = idx / (48 * NP);
    const float* src = x + (((size_t)(b * 3 + c) * 224 + (p / 14) * 16 + ph) * 224
                            + (p % 14) * 16);
    u16* dst = patches + ((size_t)b * 256 + p) * CK + c * 256 + ph * 16;
    float4 f0 = *reinterpret_cast<const float4*>(src);
    float4 f1 = *reinterpret_cast<const float4*>(src + 4);
    float4 f2 = *reinterpret_cast<const float4*>(src + 8);
    float4 f3 = *reinterpret_cast<const float4*>(src + 12);
    uint4 o0, o1;
    o0.x = (u32)f2bf(f0.x) | ((u32)f2bf(f0.y) << 16);
    o0.y = (u32)f2bf(f0.z) | ((u32)f2bf(f0.w) << 16);
    o0.z = (u32)f2bf(f1.x) | ((u32)f2bf(f1.y) << 16);
    o0.w = (u32)f2bf(f1.z) | ((u32)f2bf(f1.w) << 16);
    o1.x = (u32)f2bf(f2.x) | ((u32)f2bf(f2.y) << 16);
    o1.y = (u32)f2bf(f2.z) | ((u32)f2bf(f2.w) << 16);
    o1.z = (u32)f2bf(f3.x) | ((u32)f2bf(f3.y) << 16);
    o1.w = (u32)f2bf(f3.z) | ((u32)f2bf(f3.w) << 16);
    *reinterpret_cast<uint4*>(dst)     = o0;
    *reinterpret_cast<uint4*>(dst + 8) = o1;
}

// ---------------- gate2: top-2, probs, loss, eid, expert-sorted perm ----------------
__global__ __launch_bounds__(512) void gate2_kernel(
    const float* __restrict__ gCl,
    const float* __restrict__ gSd,
    const float* __restrict__ gNy,
    int* __restrict__ eid,
    int* __restrict__ perm,
    float* __restrict__ loss_out)
{
    __shared__ float sNy[NB][NE];
    __shared__ float sProb[NB][NE];
    __shared__ int   sTop[NB];
    __shared__ float sImp[NE], sLoad[NE];
    const int t = threadIdx.x;
    const int b = t >> 3, e = t & 7;
    float cl = gCl[t], sd = gSd[t], ny = gNy[t];
    sNy[b][e] = ny;
    __syncthreads();
    float v1 = -1e30f, v2 = -1e30f; int i1 = 0;
    #pragma unroll
    for (int k2 = 0; k2 < NE; ++k2) {
        float v = sNy[b][k2];
        if (v > v1) { v2 = v1; v1 = v; i1 = k2; }
        else if (v > v2) { v2 = v; }
    }
    if (e == 0) { sTop[b] = i1; eid[b] = i1; }
    float thr = (ny > v2) ? v2 : v1;
    float z = (cl - thr) / sd;
    sProb[b][e] = 0.5f * (1.0f + erff(z * 0.7071067811865476f));
    __syncthreads();
    if (t < NE) {
        float imp = 0.f, ld = 0.f;
        for (int i = 0; i < NB; ++i) {
            imp += (sTop[i] == t) ? 1.0f : 0.0f;
            ld  += sProb[i][t];
        }
        sImp[t] = imp; sLoad[t] = ld;
    }
    __syncthreads();
    if (t == 0) {
        float mi = 0.f, ml = 0.f;
        for (int k2 = 0; k2 < NE; ++k2) { mi += sImp[k2]; ml += sLoad[k2]; }
        mi *= (1.0f / NE); ml *= (1.0f / NE);
        float vi = 0.f, vl = 0.f;
        for (int k2 = 0; k2 < NE; ++k2) {
            float d1 = sImp[k2] - mi;  vi += d1 * d1;
            float d2 = sLoad[k2] - ml; vl += d2 * d2;
        }
        vi *= (1.0f / (NE - 1)); vl *= (1.0f / (NE - 1));  // ddof=1
        loss_out[0] = (vi / (mi * mi + 1e-10f) + vl / (ml * ml + 1e-10f)) * 0.01f;
        int off[NE]; int s = 0;
        #pragma unroll
        for (int k2 = 0; k2 < NE; ++k2) { off[k2] = s; s += (int)sImp[k2]; }
        for (int i = 0; i < NB; ++i) perm[off[sTop[i]]++] = i;
    }
}

// ---------------- 8-phase 256x256 expert GEMM (m201 schedule port) ----------------
// 192 blocks = (image via perm, n-tile 0..2); 512 thr = 8 waves (2M x 4N),
// wave tile 128x64; BK=64, 12 K-tiles; LDS 128KB = 2 buf x (A 32K | B 32K).
// A halves: E=rows{0-63,128-191}, L=rows{64-127,192-255} (consumption-aligned);
// B halves: by k 32-slice. Per phase: stage 1 half (2 gload16 into region freed
// at prev phase's end-barrier), 8 swizzled ds_read_b128, setprio+16 MFMA,
// [vmcnt(4) @ ph3/ph7], barrier. Swizzles: A chunk ^= row&7, B chunk ^= row&3
// (pre-swizzled global src, same XOR on reads).
__global__ void __launch_bounds__(512, 2) gemm_kernel(
    const u16* __restrict__ patches,
    const u16* __restrict__ wbf,
    const float* __restrict__ b_exp,
    const int* __restrict__ eid,
    const int* __restrict__ perm,
    float* __restrict__ out)
{
    extern __shared__ char sm[];   // 131072

    const int id = blockIdx.x;
    const int v  = (id & 7) * 24 + (id >> 3);   // 192 = 8*24, bijective
    const int b  = perm[v / 3];
    const int n0 = (v % 3) * 256;
    const int e  = eid[b];

    const int t  = threadIdx.x;
    const int l  = t & 63;
    const int w  = t >> 6;        // 0..7
    const int wm = w >> 2;        // 0..1
    const int wn = w & 3;         // 0..3

    // ---- staging addresses ----
    const u32 dA = (u32)(w * 2048 + l * 16);    // chunk (w*2+j) at j*1024
    int rE0, rE1;
    { int c2 = w * 2;     rE0 = (c2 < 8) ? c2 * 8 + (l >> 3) : 128 + (c2 - 8) * 8 + (l >> 3); }
    { int c2 = w * 2 + 1; rE1 = (c2 < 8) ? c2 * 8 + (l >> 3) : 128 + (c2 - 8) * 8 + (l >> 3); }
    int rL0 = rE0 + 64; if (rL0 > 195) rL0 = 195;   // pad rows never stored
    int rL1 = rE1 + 64; if (rL1 > 195) rL1 = 195;
    const u32 swA = (u32)(((l & 7) ^ (l >> 3)) * 8);
    const u16* aE0 = patches + ((size_t)b * 256 + rE0) * CK + swA;
    const u16* aE1 = patches + ((size_t)b * 256 + rE1) * CK + swA;
    const u16* aL0 = patches + ((size_t)b * 256 + rL0) * CK + swA;
    const u16* aL1 = patches + ((size_t)b * 256 + rL1) * CK + swA;
    const u32 swB = (u32)(((l & 3) ^ ((l >> 2) & 3)) * 8);
    const u16* bB0 = wbf + (size_t)e * ESTR + ((size_t)n0 + (w * 2) * 16 + (l >> 2)) * CK + swB;
    const u16* bB1 = wbf + (size_t)e * ESTR + ((size_t)n0 + (w * 2 + 1) * 16 + (l >> 2)) * CK + swB;

    // ---- ds_read offsets ----
    u32 armBase[4], brnBase[4], ack[2];
    #pragma unroll
    for (int fm = 0; fm < 4; ++fm)
        armBase[fm] = (u32)(wm * 8192 + (fm * 16 + (l & 15)) * 128);
    ack[0] = (u32)((((l >> 4)) ^ (l & 7)) * 16);
    ack[1] = (u32)(((4 + (l >> 4)) ^ (l & 7)) * 16);
    #pragma unroll
    for (int fn = 0; fn < 4; ++fn)
        brnBase[fn] = 32768u + (u32)((wn * 64 + fn * 16 + (l & 15)) * 64
                     + (((l >> 4) ^ (l & 3)) * 16));

    f32x4 acc[8][4];
    #pragma unroll
    for (int mq = 0; mq < 8; ++mq)
        #pragma unroll
        for (int fn = 0; fn < 4; ++fn)
            acc[mq][fn] = (f32x4){0.f, 0.f, 0.f, 0.f};

    auto stA = [&](u32 P, u32 half, int kt) {
        char* d = sm + P * 65536u + half * 16384u + dA;
        gload16((half ? aL0 : aE0) + kt * 64, d);
        gload16((half ? aL1 : aE1) + kt * 64, d + 1024);
    };
    auto stB = [&](u32 P, u32 kh, int kt) {
        char* d = sm + P * 65536u + 32768u + kh * 16384u + dA;
        gload16(bB0 + kt * 64 + kh * 32, d);
        gload16(bB1 + kt * 64 + kh * 32, d + 1024);
    };
    auto compute = [&](u32 P, int MH, int KS) {
        bf16x8 af[4], bfr[4];
        #pragma unroll
        for (int fm = 0; fm < 4; ++fm)
            af[fm] = *reinterpret_cast<const bf16x8*>(
                sm + P * 65536u + (u32)(MH * 16384) + armBase[fm] + ack[KS]);
        #pragma unroll
        for (int fn = 0; fn < 4; ++fn)
            bfr[fn] = *reinterpret_cast<const bf16x8*>(
                sm + P * 65536u + (u32)(KS * 16384) + brnBase[fn]);
        __builtin_amdgcn_s_setprio(1);
        #pragma unroll
        for (int fm = 0; fm < 4; ++fm)
            #pragma unroll
            for (int fn = 0; fn < 4; ++fn)
                acc[MH * 4 + fm][fn] = __builtin_amdgcn_mfma_f32_16x16x32_bf16(
                    af[fm], bfr[fn], acc[MH * 4 + fm][fn], 0, 0, 0);
        __builtin_amdgcn_s_setprio(0);
    };
    auto pend = [&](bool wait) {
        if (wait) asm volatile("s_waitcnt vmcnt(4)" ::: "memory");
        __builtin_amdgcn_sched_barrier(0);
        __builtin_amdgcn_s_barrier();
        __builtin_amdgcn_sched_barrier(0);
    };

    // ---- prologue: buf0 <- kt0 (4 halves), buf1 <- kt1 {A-E, B-k0} ----
    stA(0, 0, 0); stB(0, 0, 0); stA(0, 1, 0); stB(0, 1, 0);
    stA(1, 0, 1); stB(1, 0, 1);
    pend(true);   // vmcnt(4): buf0 landed; buf1's 4 loads in flight

    // ---- main loop: 6 iters x 8 phases = 12 K-tiles ----
    #pragma unroll 1
    for (int i = 0; i < 6; ++i) {
        const int kt = 2 * i;
        const int k2 = (kt + 2 > 11) ? 11 : kt + 2;   // clamped: junk into freed regions
        const int k3 = (kt + 3 > 11) ? 11 : kt + 3;
        stA(1, 1, kt + 1); compute(0, 0, 0); pend(false);   // ph0
        stB(1, 1, kt + 1); compute(0, 0, 1); pend(false);   // ph1
        stA(0, 0, k2);     compute(0, 1, 0); pend(false);   // ph2
        stB(0, 0, k2);     compute(0, 1, 1); pend(true);    // ph3: drain buf1 inputs
        stA(0, 1, k2);     compute(1, 0, 0); pend(false);   // ph4
        stB(0, 1, k2);     compute(1, 0, 1); pend(false);   // ph5
        stA(1, 0, k3);     compute(1, 1, 0); pend(false);   // ph6
        stB(1, 0, k3);     compute(1, 1, 1); pend(true);    // ph7: drain buf0 inputs
    }
    asm volatile("s_waitcnt vmcnt(0)" ::: "memory");   // retire stray stages

    // ---- store: bias + eps-replace, rows < 196 ----
    const int r4 = (l >> 4) * 4;
    #pragma unroll
    for (int mq = 0; mq < 8; ++mq) {
        const int mb = wm * 128 + (mq >> 2) * 64 + (mq & 3) * 16 + r4;
        #pragma unroll
        for (int fn = 0; fn < 4; ++fn) {
            const int col = n0 + wn * 64 + fn * 16 + (l & 15);
            const float bias = b_exp[e * CN + col];
            #pragma unroll
            for (int q = 0; q < 4; ++q) {
                const int mrow = mb + q;
                if (mrow < NP) {
                    float vv = acc[mq][fn][q] + bias;
                    if (vv == 0.0f) vv = 2.220446049250313e-16f;
                    out[((size_t)b * NP + mrow) * CN + col] = vv;
                }
            }
        }
    }
}

extern "C" void kernel_launch(void* const* d_in, const int* in_sizes, int n_in,
                              void* d_out, int out_size, void* d_ws, size_t ws_size,
                              hipStream_t stream) {
    const float* x       = (const float*)d_in[0];
    const float* g       = (const float*)d_in[1];
    const float* noise   = (const float*)d_in[2];
    const float* w_gate  = (const float*)d_in[3];
    const float* w_noise = (const float*)d_in[4];
    const float* w_exp   = (const float*)d_in[5];
    const float* b_exp   = (const float*)d_in[6];
    float* out = (float*)d_out;

    char* ws = (char*)d_ws;
    int*   eid     = (int*)ws;                    // 256 B
    int*   perm    = (int*)(ws + 256);            // 256 B
    float* gCl     = (float*)(ws + 512);
    float* gSd     = (float*)(ws + 2560);
    float* gNy     = (float*)(ws + 4608);
    u16*   patches = (u16*)(ws + 8192);                               // 64*256*768*2
    u16*   wbf     = (u16*)(ws + 8192 + (size_t)NB * 256 * CK * 2);   // 8*768*768*2

    hipFuncSetAttribute((const void*)gemm_kernel,
                        hipFuncAttributeMaxDynamicSharedMemorySize, 131072);

    hipLaunchKernelGGL(prep1_kernel,
                       dim3(GATE_BLOCKS + WCONV_BLOCKS + PATCH_BLOCKS), dim3(256), 0, stream,
                       x, g, noise, w_gate, w_noise, w_exp, gCl, gSd, gNy, patches, wbf);
    hipLaunchKernelGGL(gate2_kernel, dim3(1), dim3(512), 0, stream,
                       gCl, gSd, gNy, eid, perm, out + (size_t)NB * NP * CN);
    hipLaunchKernelGGL(gemm_kernel, dim3(192), dim3(512), 131072, stream,
                       patches, wbf, b_exp, eid, perm, out);
}

// Round 11
// 67.197 us; speedup vs baseline: 1.5470x; 1.0839x over previous
//
#include <hip/hip_runtime.h>
#include <math.h>

typedef unsigned short u16;
typedef unsigned int   u32;

using bf16x8 = __attribute__((ext_vector_type(8))) short;
using f32x4  = __attribute__((ext_vector_type(4))) float;

#define NB   64
#define NE   8
#define DIN  320
#define NP   196
#define CK   768
#define CN   768
#define NKT  24      // K-chunks of 32

#define GATE_BLOCKS  8
#define WPACK_BLOCKS 2304   // 8*48*24 chunks * 64 lanes / 256
#define APACK_BLOCKS 1024   // 64 images x 16 frag-rows

__device__ __forceinline__ u16 f2bf(float f) {
    u32 u = __builtin_bit_cast(u32, f);
    u += 0x7fffu + ((u >> 16) & 1u);
    return (u16)(u >> 16);
}

// ---------------- prep1: gate1 + B-pack + A-pack patchify ----------------
// packed chunk = 1KB: lane l holds 16B = 8 bf16 along k;
//   A chunk(b, fr, kb): row = fr*16 + (l&15), k = kb*32 + (l>>4)*8
//   B chunk(e, fnG, kb): col = fnG*16 + (l&15), k = kb*32 + (l>>4)*8
__global__ __launch_bounds__(256) void prep1_kernel(
    const float* __restrict__ x,
    const float* __restrict__ g,
    const float* __restrict__ noise,
    const float* __restrict__ w_gate,
    const float* __restrict__ w_noise,
    const float* __restrict__ w_exp,
    float* __restrict__ gCl, float* __restrict__ gSd, float* __restrict__ gNy,
    u16* __restrict__ apk,
    u16* __restrict__ wpk)
{
    __shared__ char smem[24704];    // union: gate 23KB | apack 24KB
    const int t = threadIdx.x;
    int bid = blockIdx.x;

    if (bid < GATE_BLOCKS) {
        // gate stage 1: 8 blocks x 8 images; thread=(pair,q), q sums 80 dims
        float (*sW)[NE + 1]  = (float (*)[NE + 1])smem;
        float (*sWn)[NE + 1] = sW + DIN;
        for (int i = t; i < DIN * NE; i += 256) {
            sW[i >> 3][i & 7]  = w_gate[i];
            sWn[i >> 3][i & 7] = w_noise[i];
        }
        __syncthreads();
        const int pair = t >> 2, q = t & 3;
        const int bl = pair >> 3, e = pair & 7;
        const int b = bid * 8 + bl;
        float cl = 0.f, nz = 0.f;
        const float* gr = g + b * DIN + q * 80;
        #pragma unroll 4
        for (int j = 0; j < 80; ++j) {
            float gv = gr[j];
            cl = fmaf(gv, sW[q * 80 + j][e], cl);
            nz = fmaf(gv, sWn[q * 80 + j][e], nz);
        }
        cl += __shfl_xor(cl, 1); cl += __shfl_xor(cl, 2);
        nz += __shfl_xor(nz, 1); nz += __shfl_xor(nz, 2);
        if (q == 0) {
            int p = b * NE + e;
            // jax.nn.softplus == max(x,0)+log1p(exp(-|x|))
            float sd = fmaxf(nz, 0.f) + log1pf(expf(-fabsf(nz))) + 0.01f;
            gCl[p] = cl; gSd[p] = sd;
            gNy[p] = fmaf(noise[p], sd, cl);
        }
        return;
    }
    bid -= GATE_BLOCKS;

    if (bid < WPACK_BLOCKS) {
        // B-pack: thread = (chunk, lane)
        int idx = bid * 256 + t;
        int chunk = idx >> 6, l = idx & 63;
        int e   = chunk / 1152;
        int rem = chunk % 1152;
        int fnG = rem / 24;
        int kb  = rem % 24;
        const float* src = w_exp + ((size_t)(e * CN + fnG * 16 + (l & 15))) * CK
                         + kb * 32 + (l >> 4) * 8;
        float4 f0 = *reinterpret_cast<const float4*>(src);
        float4 f1 = *reinterpret_cast<const float4*>(src + 4);
        uint4 o;
        o.x = (u32)f2bf(f0.x) | ((u32)f2bf(f0.y) << 16);
        o.y = (u32)f2bf(f0.z) | ((u32)f2bf(f0.w) << 16);
        o.z = (u32)f2bf(f1.x) | ((u32)f2bf(f1.y) << 16);
        o.w = (u32)f2bf(f1.z) | ((u32)f2bf(f1.w) << 16);
        *reinterpret_cast<uint4*>(wpk + (size_t)chunk * 512 + l * 8) = o;
        return;
    }
    bid -= WPACK_BLOCKS;

    // ---- A-pack patchify (R9-verified): block = (image b, frag-row fr) ----
    {
        char* pk = smem;   // 24KB staging
        const int b  = bid >> 4;
        const int fr = bid & 15;
        #pragma unroll
        for (int s = 0; s < 3; ++s) {
            int u  = t + s * 256;            // u = (lr*3 + c)*16 + ph
            int lr = u / 48;
            int c  = (u >> 4) % 3;
            int ph = u & 15;
            int p  = fr * 16 + lr; if (p > NP - 1) p = NP - 1;  // pad rows: dup of 195
            const float* src = x + ((size_t)(b * 3 + c) * 224 + (p / 14) * 16 + ph) * 224
                                 + (p % 14) * 16;
            float4 f0 = *reinterpret_cast<const float4*>(src);
            float4 f1 = *reinterpret_cast<const float4*>(src + 4);
            float4 f2 = *reinterpret_cast<const float4*>(src + 8);
            float4 f3 = *reinterpret_cast<const float4*>(src + 12);
            uint4 o0, o1;
            o0.x = (u32)f2bf(f0.x) | ((u32)f2bf(f0.y) << 16);
            o0.y = (u32)f2bf(f0.z) | ((u32)f2bf(f0.w) << 16);
            o0.z = (u32)f2bf(f1.x) | ((u32)f2bf(f1.y) << 16);
            o0.w = (u32)f2bf(f1.z) | ((u32)f2bf(f1.w) << 16);
            o1.x = (u32)f2bf(f2.x) | ((u32)f2bf(f2.y) << 16);
            o1.y = (u32)f2bf(f2.z) | ((u32)f2bf(f2.w) << 16);
            o1.z = (u32)f2bf(f3.x) | ((u32)f2bf(f3.y) << 16);
            o1.w = (u32)f2bf(f3.z) | ((u32)f2bf(f3.w) << 16);
            // k = c*256 + ph*16 + pw -> kb = c*8 + (ph>>1), lk0 = (ph&1)*2
            u32 base = (u32)((c * 8 + (ph >> 1)) * 1024 + ((ph & 1) * 2) * 256 + lr * 16);
            *reinterpret_cast<uint4*>(pk + base)       = o0;
            *reinterpret_cast<uint4*>(pk + base + 256) = o1;
        }
        __syncthreads();
        char* dst = (char*)apk + ((size_t)(b * 16 + fr) * 24) * 1024;
        #pragma unroll
        for (int s = 0; s < 6; ++s)
            *reinterpret_cast<uint4*>(dst + t * 16 + s * 4096) =
                *reinterpret_cast<const uint4*>(pk + t * 16 + s * 4096);
    }
}

// ---------------- gate2: top-2, probs, loss, eid, expert-sorted perm ----------------
__global__ __launch_bounds__(512) void gate2_kernel(
    const float* __restrict__ gCl,
    const float* __restrict__ gSd,
    const float* __restrict__ gNy,
    int* __restrict__ eid,
    int* __restrict__ perm,
    float* __restrict__ loss_out)
{
    __shared__ float sNy[NB][NE];
    __shared__ float sProb[NB][NE];
    __shared__ int   sTop[NB];
    __shared__ float sImp[NE], sLoad[NE];
    const int t = threadIdx.x;            // 512 = one (b,e) pair each
    const int b = t >> 3, e = t & 7;
    float cl = gCl[t], sd = gSd[t], ny = gNy[t];
    sNy[b][e] = ny;
    __syncthreads();
    float v1 = -1e30f, v2 = -1e30f; int i1 = 0;
    #pragma unroll
    for (int k2 = 0; k2 < NE; ++k2) {
        float v = sNy[b][k2];
        if (v > v1) { v2 = v1; v1 = v; i1 = k2; }
        else if (v > v2) { v2 = v; }
    }
    if (e == 0) { sTop[b] = i1; eid[b] = i1; }
    // is_in: noisy > 2nd-largest (thr_in=v2); else threshold = largest (v1)
    float thr = (ny > v2) ? v2 : v1;
    float z = (cl - thr) / sd;
    sProb[b][e] = 0.5f * (1.0f + erff(z * 0.7071067811865476f));
    __syncthreads();
    if (t < NE) {
        float imp = 0.f, ld = 0.f;
        for (int i = 0; i < NB; ++i) {
            imp += (sTop[i] == t) ? 1.0f : 0.0f;
            ld  += sProb[i][t];
        }
        sImp[t] = imp; sLoad[t] = ld;
    }
    __syncthreads();
    if (t == 0) {
        float mi = 0.f, ml = 0.f;
        for (int k2 = 0; k2 < NE; ++k2) { mi += sImp[k2]; ml += sLoad[k2]; }
        mi *= (1.0f / NE); ml *= (1.0f / NE);
        float vi = 0.f, vl = 0.f;
        for (int k2 = 0; k2 < NE; ++k2) {
            float d1 = sImp[k2] - mi;  vi += d1 * d1;
            float d2 = sLoad[k2] - ml; vl += d2 * d2;
        }
        vi *= (1.0f / (NE - 1)); vl *= (1.0f / (NE - 1));  // ddof=1
        loss_out[0] = (vi / (mi * mi + 1e-10f) + vl / (ml * ml + 1e-10f)) * 0.01f;
        // expert-sorted stable permutation of images (L2 locality for B)
        int off[NE]; int s = 0;
        #pragma unroll
        for (int k2 = 0; k2 < NE; ++k2) { off[k2] = s; s += (int)sImp[k2]; }
        for (int i = 0; i < NB; ++i) perm[off[sTop[i]]++] = i;
    }
}

// ---------------- fully-packed reg-streaming expert GEMM: no LDS, no barriers ----------------
// 768 blocks -> (sorted slot -> image, m-tile 0/1, n-tile 0..5); 4 waves, each
// owns a 64x64 tile. Every fragment load = ONE contiguous 1KB wave-load
// (global_load_dwordx4, lane offset l*16) from the packed A/B chunk arrays.
// Register double-buffered K-loop, manual 2x unroll, setprio on MFMA clusters.
__global__ __launch_bounds__(256) void gemm_kernel(
    const u16* __restrict__ apk,
    const u16* __restrict__ wpk,
    const float* __restrict__ b_exp,
    const int* __restrict__ eid,
    const int* __restrict__ perm,
    float* __restrict__ out)
{
    const int id = blockIdx.x;
    // bijective XCD swizzle: 96 consecutive virtual blocks (=8 sorted slots) per XCD
    const int v  = (id & 7) * 96 + (id >> 3);
    const int b  = perm[v / 12];
    const int rr = v % 12;
    const int mt = rr / 6;
    const int nt = rr % 6;
    const int e  = eid[b];

    const int t  = threadIdx.x;
    const int l  = t & 63;
    const int w  = t >> 6;
    const int wm = w >> 1;        // m half of 128-tile
    const int wn = w & 1;         // n half of 128-tile

    // packed chunk bases; K-step advances by 1024 B
    const char* aB[4];
    const char* bB[4];
    #pragma unroll
    for (int fm = 0; fm < 4; ++fm)
        aB[fm] = (const char*)apk
               + ((size_t)((b * 16 + mt * 8 + wm * 4 + fm) * 24)) * 1024 + l * 16;
    #pragma unroll
    for (int fn = 0; fn < 4; ++fn)
        bB[fn] = (const char*)wpk
               + ((size_t)((e * 48 + nt * 8 + wn * 4 + fn) * 24)) * 1024 + l * 16;

    f32x4 acc[4][4];
    #pragma unroll
    for (int fm = 0; fm < 4; ++fm)
        #pragma unroll
        for (int fn = 0; fn < 4; ++fn)
            acc[fm][fn] = (f32x4){0.f, 0.f, 0.f, 0.f};

    bf16x8 aE[4], bE[4], aO[4], bO[4];
    #pragma unroll
    for (int f = 0; f < 4; ++f) {
        aE[f] = *reinterpret_cast<const bf16x8*>(aB[f]);
        bE[f] = *reinterpret_cast<const bf16x8*>(bB[f]);
    }

    int kt = 0;
    for (; kt < NKT - 2; kt += 2) {
        #pragma unroll
        for (int f = 0; f < 4; ++f) {
            aO[f] = *reinterpret_cast<const bf16x8*>(aB[f] + (kt + 1) * 1024);
            bO[f] = *reinterpret_cast<const bf16x8*>(bB[f] + (kt + 1) * 1024);
        }
        __builtin_amdgcn_s_setprio(1);
        #pragma unroll
        for (int fm = 0; fm < 4; ++fm)
            #pragma unroll
            for (int fn = 0; fn < 4; ++fn)
                acc[fm][fn] = __builtin_amdgcn_mfma_f32_16x16x32_bf16(
                    aE[fm], bE[fn], acc[fm][fn], 0, 0, 0);
        __builtin_amdgcn_s_setprio(0);
        #pragma unroll
        for (int f = 0; f < 4; ++f) {
            aE[f] = *reinterpret_cast<const bf16x8*>(aB[f] + (kt + 2) * 1024);
            bE[f] = *reinterpret_cast<const bf16x8*>(bB[f] + (kt + 2) * 1024);
        }
        __builtin_amdgcn_s_setprio(1);
        #pragma unroll
        for (int fm = 0; fm < 4; ++fm)
            #pragma unroll
            for (int fn = 0; fn < 4; ++fn)
                acc[fm][fn] = __builtin_amdgcn_mfma_f32_16x16x32_bf16(
                    aO[fm], bO[fn], acc[fm][fn], 0, 0, 0);
        __builtin_amdgcn_s_setprio(0);
    }
    // tail: kt == NKT-2
    {
        #pragma unroll
        for (int f = 0; f < 4; ++f) {
            aO[f] = *reinterpret_cast<const bf16x8*>(aB[f] + (NKT - 1) * 1024);
            bO[f] = *reinterpret_cast<const bf16x8*>(bB[f] + (NKT - 1) * 1024);
        }
        __builtin_amdgcn_s_setprio(1);
        #pragma unroll
        for (int fm = 0; fm < 4; ++fm)
            #pragma unroll
            for (int fn = 0; fn < 4; ++fn)
                acc[fm][fn] = __builtin_amdgcn_mfma_f32_16x16x32_bf16(
                    aE[fm], bE[fn], acc[fm][fn], 0, 0, 0);
        #pragma unroll
        for (int fm = 0; fm < 4; ++fm)
            #pragma unroll
            for (int fn = 0; fn < 4; ++fn)
                acc[fm][fn] = __builtin_amdgcn_mfma_f32_16x16x32_bf16(
                    aO[fm], bO[fn], acc[fm][fn], 0, 0, 0);
        __builtin_amdgcn_s_setprio(0);
    }

    // ---- store: bias + eps-replace, rows < 196 only ----
    const int r4 = (l >> 4) * 4;
    #pragma unroll
    for (int fm = 0; fm < 4; ++fm) {
        int mb = mt * 128 + wm * 64 + fm * 16 + r4;
        #pragma unroll
        for (int fn = 0; fn < 4; ++fn) {
            int col = nt * 128 + wn * 64 + fn * 16 + (l & 15);
            float bias = b_exp[e * CN + col];
            #pragma unroll
            for (int q = 0; q < 4; ++q) {
                int mrow = mb + q;
                if (mrow < NP) {
                    float vv = acc[fm][fn][q] + bias;
                    if (vv == 0.0f) vv = 2.220446049250313e-16f;
                    out[((size_t)b * NP + mrow) * CN + col] = vv;
                }
            }
        }
    }
}

extern "C" void kernel_launch(void* const* d_in, const int* in_sizes, int n_in,
                              void* d_out, int out_size, void* d_ws, size_t ws_size,
                              hipStream_t stream) {
    const float* x       = (const float*)d_in[0];
    const float* g       = (const float*)d_in[1];
    const float* noise   = (const float*)d_in[2];
    const float* w_gate  = (const float*)d_in[3];
    const float* w_noise = (const float*)d_in[4];
    const float* w_exp   = (const float*)d_in[5];
    const float* b_exp   = (const float*)d_in[6];
    float* out = (float*)d_out;

    char* ws = (char*)d_ws;
    int*   eid  = (int*)ws;                     // 256 B
    int*   perm = (int*)(ws + 256);             // 256 B
    float* gCl  = (float*)(ws + 512);
    float* gSd  = (float*)(ws + 2560);
    float* gNy  = (float*)(ws + 4608);
    u16*   apk  = (u16*)(ws + 8192);                          // 64*16*24*1024 = 25.2 MB
    u16*   wpk  = (u16*)(ws + 8192 + (size_t)64 * 16 * 24 * 1024);  // 9216*1024 = 9.4 MB

    hipLaunchKernelGGL(prep1_kernel,
                       dim3(GATE_BLOCKS + WPACK_BLOCKS + APACK_BLOCKS), dim3(256), 0, stream,
                       x, g, noise, w_gate, w_noise, w_exp, gCl, gSd, gNy, apk, wpk);
    hipLaunchKernelGGL(gate2_kernel, dim3(1), dim3(512), 0, stream,
                       gCl, gSd, gNy, eid, perm, out + (size_t)NB * NP * CN);
    hipLaunchKernelGGL(gemm_kernel, dim3(768), dim3(256), 0, stream,
                       apk, wpk, b_exp, eid, perm, out);
}